// Round 2
// baseline (310.804 us; speedup 1.0000x reference)
//
#include <hip/hip_runtime.h>
#include <math.h>

#define NANCH 87296
#define NF 4256        // 1000*4 + 256 finalists
#define CAPD 128       // max neighbors per column
#define NBINS 65536
#define NITER 16       // 15 scan iterations + initial keep
#define BCAP 2048      // boundary-bin buffer per level
#define EC 12288       // LDS edge cap for k7 CSR copy

struct InPtrs {
    const float* cls[5];
    const float* reg[5];
    const float* loc;
};

// workspace layout
constexpr size_t SZ_HIST  = 5ull * NBINS * 4;
constexpr size_t OFF_HIST = 0;
constexpr size_t OFF_CNT  = OFF_HIST + SZ_HIST;
constexpr size_t OFF_CTR  = OFF_CNT + (size_t)NF * 4;
constexpr size_t ZERO_SZ  = OFF_CTR + 64;
constexpr size_t OFF_SBITS = ((ZERO_SZ + 255) / 256) * 256;
constexpr size_t OFF_CLSV  = OFF_SBITS + (size_t)NANCH * 4;
constexpr size_t OFF_PAR   = OFF_CLSV + (size_t)NANCH * 4;
constexpr size_t OFF_FINK  = ((OFF_PAR + 64 + 255) / 256) * 256;
constexpr size_t OFF_BBUF  = OFF_FINK + (size_t)NF * 8;
constexpr size_t OFF_SBOX  = OFF_BBUF + 5ull * BCAP * 8;
constexpr size_t OFF_SSC   = OFF_SBOX + (size_t)NF * 16;
constexpr size_t OFF_SCV   = OFF_SSC + (size_t)NF * 4;
constexpr size_t OFF_SAR   = OFF_SCV + (size_t)NF * 4;
constexpr size_t OFF_NBR   = OFF_SAR + (size_t)NF * 4;

__device__ __forceinline__ void lvl_of(int a, int& lev, int& idx) {
    if (a < 65536)      { lev = 0; idx = a; }
    else if (a < 81920) { lev = 1; idx = a - 65536; }
    else if (a < 86016) { lev = 2; idx = a - 81920; }
    else if (a < 87040) { lev = 3; idx = a - 86016; }
    else                { lev = 4; idx = a - 87040; }
}

__device__ __forceinline__ unsigned int fkey(float f) {
    unsigned int u = __float_as_uint(f);
    return u ^ ((u & 0x80000000u) ? 0xFFFFFFFFu : 0x80000000u);
}
__device__ __forceinline__ float funkey(unsigned int k) {
    return __uint_as_float(k ^ ((k & 0x80000000u) ? 0x80000000u : 0xFFFFFFFFu));
}

// ---------------------------------------------------------------- K1
// 4 threads per anchor. Thread k of a quad reads float4 indices q*4+k so the
// 4-lane group covers one contiguous 64B line per q-step (16 lines / wave
// load instead of 64). Quad-reduce via shfl_xor; tie -> smaller class index
// (matches numpy argmax first-occurrence).
__global__ __launch_bounds__(256) void k1_score(InPtrs P, unsigned int* hist,
        unsigned int* sbits, unsigned int* clsv) {
    int g = blockIdx.x * 256 + threadIdx.x;
    int a = g >> 2;
    int k = g & 3;
    if (a >= NANCH) return;
    int lev, idx; lvl_of(a, lev, idx);
    const float4* row = (const float4*)(P.cls[lev] + (size_t)idx * 80);
    float best = -INFINITY; int bi = 0;
    #pragma unroll
    for (int q = 0; q < 5; ++q) {
        float4 v = row[q * 4 + k];
        int c0 = q * 16 + k * 4;
        if (v.x > best) { best = v.x; bi = c0 + 0; }
        if (v.y > best) { best = v.y; bi = c0 + 1; }
        if (v.z > best) { best = v.z; bi = c0 + 2; }
        if (v.w > best) { best = v.w; bi = c0 + 3; }
    }
    #pragma unroll
    for (int m = 1; m < 4; m <<= 1) {
        float ob = __shfl_xor(best, m, 64);
        int  obi = __shfl_xor(bi, m, 64);
        if (ob > best || (ob == best && obi < bi)) { best = ob; bi = obi; }
    }
    if (k == 0) {
        float score = 1.0f / (1.0f + expf(-best));
        unsigned int valid = (score > 0.05f) ? 1u : 0u;
        float psm = valid ? score : -1.0f;
        unsigned int sb = fkey(psm);
        sbits[a] = sb;
        clsv[a] = (unsigned int)(bi + 1) | (valid << 31);
        atomicAdd(&hist[(size_t)lev * NBINS + (sb >> 16)], 1u);
    }
}

// ---------------------------------------------------------------- K2
__global__ __launch_bounds__(1024) void k2_scan(const unsigned int* hist,
        unsigned int* params) {
    int lev = blockIdx.x;
    unsigned int K = (lev == 4) ? 256u : 1000u;
    const unsigned int* h = hist + (size_t)lev * NBINS;
    const uint4* h4 = (const uint4*)h;
    __shared__ unsigned int seg[1024];
    __shared__ unsigned int suf[1024];
    int t = threadIdx.x;
    unsigned int s = 0;
    #pragma unroll
    for (int b = 0; b < 16; ++b) {
        uint4 v = h4[t * 16 + b];
        s += v.x + v.y + v.z + v.w;
    }
    seg[t] = s;
    suf[t] = s;
    __syncthreads();
    for (int off = 1; off < 1024; off <<= 1) {
        unsigned int v = suf[t];
        unsigned int add = (t + off < 1024) ? suf[t + off] : 0u;
        __syncthreads();
        suf[t] = v + add;
        __syncthreads();
    }
    unsigned int excl = suf[t] - seg[t];
    if (excl < K && excl + seg[t] >= K) {
        unsigned int cum = excl;
        for (int b = 63; b >= 0; --b) {
            unsigned int c = h[t * 64 + b];
            if (cum + c >= K) {
                params[lev] = (unsigned int)(t * 64 + b);
                params[8 + lev] = K - cum;
                break;
            }
            cum += c;
        }
    }
}

// ---------------------------------------------------------------- K3
__global__ __launch_bounds__(256) void k3_compact(const unsigned int* sbits,
        const unsigned int* clsv, const unsigned int* params,
        unsigned long long* finKeys, unsigned int* finCount,
        unsigned long long* bBuf, unsigned int* bCount) {
    int a = blockIdx.x * blockDim.x + threadIdx.x;
    if (a >= NANCH) return;
    int lev, idx; lvl_of(a, lev, idx);
    unsigned int sb = sbits[a];
    unsigned int h16 = sb >> 16;
    unsigned int Bs = params[lev];
    if (h16 < Bs) return;
    unsigned int cv = clsv[a];
    unsigned int composite = ((unsigned int)lev << 16) | (unsigned int)idx;
    unsigned int inv = (~composite) & 0x7FFFFu;
    unsigned int low = (inv << 13) | ((cv >> 31) << 7) | (cv & 0x7Fu);
    unsigned long long key = ((unsigned long long)sb << 32) | low;
    if (h16 > Bs) {
        unsigned int p = atomicAdd(finCount, 1u);
        if (p < NF) finKeys[p] = key;
    } else {
        unsigned int p = atomicAdd(&bCount[lev], 1u);
        if (p < BCAP) bBuf[(size_t)lev * BCAP + p] = key;
    }
}

// ---------------------------------------------------------------- K4
// one block per level (appends to finCount are order-independent: k5 ranks
// globally by key afterwards).
__global__ __launch_bounds__(1024) void k4_bound(const unsigned int* params,
        const unsigned long long* bBuf, const unsigned int* bCount,
        unsigned long long* finKeys, unsigned int* finCount) {
    __shared__ unsigned long long k[BCAP];
    int t = threadIdx.x;
    int lev = blockIdx.x;
    unsigned int bc = bCount[lev];
    int n = (bc > BCAP) ? BCAP : (int)bc;
    int r = (int)params[8 + lev];
    if (r > n) r = n;
    int m = 1; while (m < n) m <<= 1;
    for (int i = t; i < m; i += 1024)
        k[i] = (i < n) ? bBuf[(size_t)lev * BCAP + i] : 0ull;
    __syncthreads();
    for (int len = 2; len <= m; len <<= 1) {
        for (int st = len >> 1; st > 0; st >>= 1) {
            for (int i = t; i < m; i += 1024) {
                int j = i ^ st;
                if (j > i) {
                    unsigned long long a = k[i], b = k[j];
                    bool up = ((i & len) == 0);
                    if (up ? (a < b) : (a > b)) { k[i] = b; k[j] = a; }
                }
            }
            __syncthreads();
        }
    }
    for (int i = t; i < r; i += 1024) {
        unsigned int p = atomicAdd(finCount, 1u);
        if (p < NF) finKeys[p] = k[i];
    }
}

// ---------------------------------------------------------------- K5
__global__ __launch_bounds__(256) void k5_rank(InPtrs P,
        const unsigned long long* finKeys, float4* sBox, float* sScore,
        unsigned int* sCV, float* sArea) {
    __shared__ unsigned long long keys[NF];
    __shared__ unsigned int rnk[64];
    int t = threadIdx.x;
    for (int i = t; i < NF; i += 256) keys[i] = finKeys[i];
    if (t < 64) rnk[t] = 0;
    __syncthreads();
    int lf = t & 63;
    int seg = t >> 6;
    int f = blockIdx.x * 64 + lf;
    unsigned long long my = (f < NF) ? keys[f] : 0ull;
    if (f < NF) {
        unsigned int c = 0;
        int s0 = seg * 1064, s1 = s0 + 1064;
        for (int i = s0; i < s1; ++i) c += (keys[i] > my) ? 1u : 0u;
        atomicAdd(&rnk[lf], c);
    }
    __syncthreads();
    if (seg == 0 && f < NF) {
        unsigned int r = rnk[lf];
        unsigned int sb  = (unsigned int)(my >> 32);
        unsigned int low = (unsigned int)my;
        unsigned int composite = (~(low >> 13)) & 0x7FFFFu;
        int lev = composite >> 16;
        int idx = composite & 0xFFFF;
        float4 b = ((const float4*)P.reg[lev])[idx];
        float vy1 = P.loc[0], vx1 = P.loc[1], vy2 = P.loc[2], vx2 = P.loc[3];
        float y1 = fmaxf(b.x, vy1), x1 = fmaxf(b.y, vx1);
        float y2 = fminf(b.z, vy2), x2 = fminf(b.w, vx2);
        float area = __fmul_rn(fmaxf(y2 - y1, 0.0f), fmaxf(x2 - x1, 0.0f));
        unsigned int valid = (low >> 7) & 1u;
        sBox[r] = make_float4(y1, x1, y2, x2);
        sScore[r] = valid ? funkey(sb) : 0.0f;
        sCV[r] = (low & 0x7Fu) | (valid << 31);
        sArea[r] = area;
    }
}

// ---------------------------------------------------------------- K6
// triangular 1D grid: only the it<=jt tiles are launched.
__global__ __launch_bounds__(256) void k6_adj(const float4* sBox,
        const float* sArea, unsigned int* cnt, unsigned short* nbr) {
    int L = blockIdx.x;
    float fr = sqrtf(8.0f * (float)L + 1.0f);
    int jt = (int)((fr - 1.0f) * 0.5f);
    while ((jt + 1) * (jt + 2) / 2 <= L) jt++;
    while (jt * (jt + 1) / 2 > L) jt--;
    int it = L - jt * (jt + 1) / 2;
    __shared__ float4 cb[64]; __shared__ float ca[64];
    __shared__ float4 rb[64]; __shared__ float ra[64];
    int t = threadIdx.x;
    if (t < 64) {
        int j = jt * 64 + t;
        if (j < NF) { cb[t] = sBox[j]; ca[t] = sArea[j]; }
        int i = it * 64 + t;
        if (i < NF) { rb[t] = sBox[i]; ra[t] = sArea[i]; }
    }
    __syncthreads();
    int lj = t & 63;
    int j = jt * 64 + lj;
    if (j >= NF) return;
    float4 B = cb[lj]; float ab = ca[lj];
    for (int li = (t >> 6); li < 64; li += 4) {
        int i = it * 64 + li;
        if (i >= j) continue;
        float4 A = rb[li]; float aa = ra[li];
        float iy1 = fmaxf(A.x, B.x), ix1 = fmaxf(A.y, B.y);
        float iy2 = fminf(A.z, B.z), ix2 = fminf(A.w, B.w);
        float ih = fmaxf(iy2 - iy1, 0.0f), iw = fmaxf(ix2 - ix1, 0.0f);
        float inter = __fmul_rn(ih, iw);
        float uni = __fsub_rn(__fadd_rn(aa, ab), inter);
        float iou = __fdiv_rn(inter, fmaxf(uni, 1e-9f));
        if (iou > 0.5f) {
            unsigned int p = atomicAdd(&cnt[j], 1u);
            if (p < CAPD) nbr[(size_t)j * CAPD + p] = (unsigned short)i;
        }
    }
}

// ---------------------------------------------------------------- K7
// adjacency staged into LDS as CSR once (iteration-invariant), then 16
// all-LDS keep iterations + top-100 emit.
__global__ __launch_bounds__(1024) void k7_nms(InPtrs P, const float4* sBox,
        const float* sScore, const unsigned int* sCV, const unsigned int* cnt,
        const unsigned short* nbr, float* out) {
    __shared__ unsigned char bufA[NF];
    __shared__ unsigned char bufB[NF];
    __shared__ unsigned int csum[1024];
    __shared__ unsigned int off[NF + 1];
    __shared__ unsigned short degs[NF];
    __shared__ unsigned short edges[EC];
    __shared__ float ploc[6];
    int t = threadIdx.x;
    if (t < 6) ploc[t] = P.loc[t];
    for (int j = t; j < NF; j += 1024) {
        unsigned int d = cnt[j]; if (d > CAPD) d = CAPD;
        degs[j] = (unsigned short)d;
        bufA[j] = 1;
    }
    __syncthreads();
    // prefix sum of degrees -> CSR offsets
    const int CH = 5;
    {
        unsigned int dq[CH]; unsigned int s = 0;
        #pragma unroll
        for (int q = 0; q < CH; ++q) {
            int j = t * CH + q;
            unsigned int d = (j < NF) ? (unsigned int)degs[j] : 0u;
            dq[q] = d; s += d;
        }
        csum[t] = s;
        __syncthreads();
        for (int o = 1; o < 1024; o <<= 1) {
            unsigned int v = csum[t];
            unsigned int add = (t >= o) ? csum[t - o] : 0u;
            __syncthreads();
            csum[t] = v + add;
            __syncthreads();
        }
        unsigned int base = csum[t] - s;
        #pragma unroll
        for (int q = 0; q < CH; ++q) {
            int j = t * CH + q;
            if (j < NF) { off[j] = base; base += dq[q]; }
        }
        if (t == 1023) off[NF] = csum[1023];
    }
    __syncthreads();
    unsigned int E = off[NF];
    bool useLds = (E <= (unsigned int)EC);
    if (useLds) {
        for (int j = t; j < NF; j += 1024) {
            unsigned int o = off[j];
            unsigned int d = degs[j];
            const unsigned short* nl = nbr + (size_t)j * CAPD;
            for (unsigned int e = 0; e < d; ++e) edges[o + e] = nl[e];
        }
    }
    __syncthreads();
    unsigned char* cur = bufA; unsigned char* nxt = bufB;
    for (int itr = 0; itr < NITER; ++itr) {
        if (useLds) {
            for (int j = t; j < NF; j += 1024) {
                unsigned int d = degs[j];
                unsigned int o = off[j];
                unsigned char kp = 1;
                for (unsigned int e = 0; e < d; ++e)
                    if (cur[edges[o + e]]) { kp = 0; break; }
                nxt[j] = kp;
            }
        } else {
            for (int j = t; j < NF; j += 1024) {
                unsigned int d = degs[j];
                const unsigned short* nl = nbr + (size_t)j * CAPD;
                unsigned char kp = 1;
                for (unsigned int e = 0; e < d; ++e)
                    if (cur[nl[e]]) { kp = 0; break; }
                nxt[j] = kp;
            }
        }
        __syncthreads();
        unsigned char* tm = cur; cur = nxt; nxt = tm;
    }
    // final keep & emit
    int base = t * CH;
    unsigned char kf[CH];
    unsigned int sum = 0;
    #pragma unroll
    for (int q = 0; q < CH; ++q) {
        int j = base + q;
        unsigned char v = 0;
        if (j < NF) v = cur[j] & (unsigned char)(sCV[j] >> 31);
        kf[q] = v; sum += v;
    }
    csum[t] = sum;
    __syncthreads();
    for (int o = 1; o < 1024; o <<= 1) {
        unsigned int v = csum[t];
        unsigned int add = (t >= o) ? csum[t - o] : 0u;
        __syncthreads();
        csum[t] = v + add;
        __syncthreads();
    }
    unsigned int keptTot = csum[1023];
    unsigned int run = csum[t] - sum;
    float vy1 = ploc[0], vx1 = ploc[1], vy2 = ploc[2], vx2 = ploc[3];
    float sy = ploc[4] / fmaxf(vy2 - vy1, 1e-6f);
    float sx = ploc[5] / fmaxf(vx2 - vx1, 1e-6f);
    #pragma unroll
    for (int q = 0; q < CH; ++q) {
        int j = base + q;
        if (j >= NF) break;
        unsigned int slot = 0xFFFFFFFFu;
        float sc = 0.0f;
        if (kf[q]) {
            if (run < 100u) { slot = run; sc = sScore[j]; }
            run++;
        } else if (keptTot < 100u) {
            unsigned int nk = (unsigned int)j - run;
            unsigned int s2 = keptTot + nk;
            if (s2 < 100u) { slot = s2; sc = 0.0f; }
        }
        if (slot < 100u) {
            float4 b = sBox[j];
            out[slot * 4 + 0] = (b.x - vy1) * sy;
            out[slot * 4 + 1] = (b.y - vx1) * sx;
            out[slot * 4 + 2] = (b.z - vy1) * sy;
            out[slot * 4 + 3] = (b.w - vx1) * sx;
            out[400 + slot] = (float)(sCV[j] & 0x7Fu);
            out[500 + slot] = sc;
        }
    }
}

extern "C" void kernel_launch(void* const* d_in, const int* in_sizes, int n_in,
                              void* d_out, int out_size, void* d_ws, size_t ws_size,
                              hipStream_t stream) {
    (void)n_in; (void)out_size; (void)ws_size;
    InPtrs P;
    bool inter = (in_sizes[1] == 65536 * 4);
    for (int s = 0; s < 5; ++s) {
        P.cls[s] = (const float*)d_in[inter ? 2 * s : s];
        P.reg[s] = (const float*)d_in[inter ? 2 * s + 1 : 5 + s];
    }
    P.loc = (const float*)d_in[10];

    char* w = (char*)d_ws;
    unsigned int* hist   = (unsigned int*)(w + OFF_HIST);
    unsigned int* cnt    = (unsigned int*)(w + OFF_CNT);
    unsigned int* ctrs   = (unsigned int*)(w + OFF_CTR);
    unsigned int* sbits  = (unsigned int*)(w + OFF_SBITS);
    unsigned int* clsv   = (unsigned int*)(w + OFF_CLSV);
    unsigned int* params = (unsigned int*)(w + OFF_PAR);
    unsigned long long* finKeys = (unsigned long long*)(w + OFF_FINK);
    unsigned long long* bBuf    = (unsigned long long*)(w + OFF_BBUF);
    float4* sBox  = (float4*)(w + OFF_SBOX);
    float* sScore = (float*)(w + OFF_SSC);
    unsigned int* sCV = (unsigned int*)(w + OFF_SCV);
    float* sArea  = (float*)(w + OFF_SAR);
    unsigned short* nbr = (unsigned short*)(w + OFF_NBR);

    hipMemsetAsync(d_ws, 0, ZERO_SZ, stream);
    k1_score<<<1364, 256, 0, stream>>>(P, hist, sbits, clsv);
    k2_scan<<<5, 1024, 0, stream>>>(hist, params);
    k3_compact<<<341, 256, 0, stream>>>(sbits, clsv, params, finKeys, ctrs, bBuf, ctrs + 1);
    k4_bound<<<5, 1024, 0, stream>>>(params, bBuf, ctrs + 1, finKeys, ctrs);
    k5_rank<<<67, 256, 0, stream>>>(P, finKeys, sBox, sScore, sCV, sArea);
    k6_adj<<<2278, 256, 0, stream>>>(sBox, sArea, cnt, nbr);
    k7_nms<<<1, 1024, 0, stream>>>(P, sBox, sScore, sCV, cnt, nbr, (float*)d_out);
}

// Round 3
// 306.960 us; speedup vs baseline: 1.0125x; 1.0125x over previous
//
#include <hip/hip_runtime.h>
#include <math.h>

#define NANCH 87296
#define NF 4256        // 1000*4 + 256 finalists
#define CAPD 128       // max neighbors per column
#define NBINS 65536
#define NITER 16       // 15 scan iterations + initial keep
#define BCAP 2048      // boundary-bin buffer per level (valid score-ties only now)
#define EC 12288       // LDS edge cap for k7 CSR copy
#define NBLK 341       // 256-anchor blocks; level boundaries are multiples of 256
#define BIN_NEG 0x407Fu  // fkey(-1.0f) >> 16

struct InPtrs {
    const float* cls[5];
    const float* reg[5];
    const float* loc;
};

// workspace layout
constexpr size_t SZ_HIST  = 5ull * NBINS * 4;
constexpr size_t OFF_HIST = 0;
constexpr size_t OFF_CNT  = OFF_HIST + SZ_HIST;
constexpr size_t OFF_CTR  = OFF_CNT + (size_t)NF * 4;   // [0]=finCount,[1..5]=bCount
constexpr size_t ZERO_SZ  = OFF_CTR + 64;
constexpr size_t OFF_SBITS = ((ZERO_SZ + 255) / 256) * 256;
constexpr size_t OFF_CLSV  = OFF_SBITS + (size_t)NANCH * 4;
constexpr size_t OFF_PAR   = OFF_CLSV + (size_t)NANCH * 4;  // B*[5]@0,r*[5]@8,rNeg[5]@16
constexpr size_t OFF_INVB  = OFF_PAR + 128;                 // per-block invalid counts
constexpr size_t OFF_INVO  = OFF_INVB + (size_t)NBLK * 4;   // scanned offsets
constexpr size_t OFF_FINK  = ((OFF_INVO + (size_t)NBLK * 4 + 255) / 256) * 256;
constexpr size_t OFF_BBUF  = OFF_FINK + (size_t)NF * 8;
constexpr size_t OFF_SBOX  = OFF_BBUF + 5ull * BCAP * 8;
constexpr size_t OFF_SSC   = OFF_SBOX + (size_t)NF * 16;
constexpr size_t OFF_SCV   = OFF_SSC + (size_t)NF * 4;
constexpr size_t OFF_SAR   = OFF_SCV + (size_t)NF * 4;
constexpr size_t OFF_NBR   = OFF_SAR + (size_t)NF * 4;

__device__ __forceinline__ void lvl_of(int a, int& lev, int& idx) {
    if (a < 65536)      { lev = 0; idx = a; }
    else if (a < 81920) { lev = 1; idx = a - 65536; }
    else if (a < 86016) { lev = 2; idx = a - 81920; }
    else if (a < 87040) { lev = 3; idx = a - 86016; }
    else                { lev = 4; idx = a - 87040; }
}

__device__ __forceinline__ unsigned int fkey(float f) {
    unsigned int u = __float_as_uint(f);
    return u ^ ((u & 0x80000000u) ? 0xFFFFFFFFu : 0x80000000u);
}
__device__ __forceinline__ float funkey(unsigned int k) {
    return __uint_as_float(k ^ ((k & 0x80000000u) ? 0x80000000u : 0xFFFFFFFFu));
}

// ---------------------------------------------------------------- K1
// 4 threads/anchor, 256 anchors/block (block never straddles a level).
// Histogram VALID anchors only (~16% — scattered bins, no hot-spot).
// Invalid anchors are counted per block with one plain store; their
// histogram contribution is synthesized arithmetically in k2. This removes
// the ~73k same-address atomicAdds that serialized at the TCC (104 us).
__global__ __launch_bounds__(1024) void k1_score(InPtrs P, unsigned int* hist,
        unsigned int* sbits, unsigned int* clsv, unsigned int* invBlk) {
    int t = threadIdx.x;
    int a = blockIdx.x * 256 + (t >> 2);
    int k = t & 3;
    int lev, idx; lvl_of(a, lev, idx);
    const float4* row = (const float4*)(P.cls[lev] + (size_t)idx * 80);
    float best = -INFINITY; int bi = 0;
    #pragma unroll
    for (int q = 0; q < 5; ++q) {
        float4 v = row[q * 4 + k];
        int c0 = q * 16 + k * 4;
        if (v.x > best) { best = v.x; bi = c0 + 0; }
        if (v.y > best) { best = v.y; bi = c0 + 1; }
        if (v.z > best) { best = v.z; bi = c0 + 2; }
        if (v.w > best) { best = v.w; bi = c0 + 3; }
    }
    #pragma unroll
    for (int m = 1; m < 4; m <<= 1) {
        float ob = __shfl_xor(best, m, 64);
        int  obi = __shfl_xor(bi, m, 64);
        if (ob > best || (ob == best && obi < bi)) { best = ob; bi = obi; }
    }
    bool lead = (k == 0);
    unsigned int valid = 0;
    if (lead) {
        float score = 1.0f / (1.0f + expf(-best));
        valid = (score > 0.05f) ? 1u : 0u;
        float psm = valid ? score : -1.0f;
        unsigned int sb = fkey(psm);
        sbits[a] = sb;
        clsv[a] = (unsigned int)(bi + 1) | (valid << 31);
        if (valid) atomicAdd(&hist[(size_t)lev * NBINS + (sb >> 16)], 1u);
    }
    __shared__ unsigned int wv[16];
    unsigned long long mv = __ballot(lead && valid);
    int lane = t & 63, w = t >> 6;
    if (lane == 0) wv[w] = (unsigned int)__popcll(mv);
    __syncthreads();
    if (t == 0) {
        unsigned int s = 0;
        #pragma unroll
        for (int i = 0; i < 16; ++i) s += wv[i];
        invBlk[blockIdx.x] = 256u - s;
    }
}

// ---------------------------------------------------------------- K2
// blocks 0-4: per-level descending bin scan over the VALID histogram.
// If total valid >= K: boundary among valid bins (B*, r*), rNeg = 0.
// Else: B* = BIN_NEG, r* = 0, rNeg = K - totValid (invalids by index).
// block 5: segmented exclusive scan of per-block invalid counts.
__global__ __launch_bounds__(1024) void k2_scan(const unsigned int* hist,
        const unsigned int* invBlk, unsigned int* params, unsigned int* invOff) {
    int t = threadIdx.x;
    if (blockIdx.x == 5) {
        __shared__ unsigned int sv[512];
        __shared__ unsigned int orig[512];
        if (t < 512) {
            unsigned int v = (t < NBLK) ? invBlk[t] : 0u;
            sv[t] = v; orig[t] = v;
        }
        __syncthreads();
        for (int off = 1; off < 512; off <<= 1) {
            unsigned int add = 0;
            if (t < 512 && t >= off) add = sv[t - off];
            __syncthreads();
            if (t < 512) sv[t] += add;
            __syncthreads();
        }
        if (t < NBLK) {
            int segStart = (t < 256) ? 0 : (t < 320) ? 256 : (t < 336) ? 320
                         : (t < 340) ? 336 : 340;
            invOff[t] = sv[t] - orig[t] - (segStart > 0 ? sv[segStart - 1] : 0u);
        }
        return;
    }
    int lev = blockIdx.x;
    unsigned int K = (lev == 4) ? 256u : 1000u;
    const unsigned int* h = hist + (size_t)lev * NBINS;
    const uint4* h4 = (const uint4*)h;
    __shared__ unsigned int seg[1024];
    __shared__ unsigned int suf[1024];
    unsigned int s = 0;
    #pragma unroll
    for (int b = 0; b < 16; ++b) {
        uint4 v = h4[t * 16 + b];
        s += v.x + v.y + v.z + v.w;
    }
    seg[t] = s;
    suf[t] = s;
    __syncthreads();
    for (int off = 1; off < 1024; off <<= 1) {
        unsigned int v = suf[t];
        unsigned int add = (t + off < 1024) ? suf[t + off] : 0u;
        __syncthreads();
        suf[t] = v + add;
        __syncthreads();
    }
    unsigned int totValid = suf[0];
    if (totValid >= K) {
        unsigned int excl = suf[t] - seg[t];
        if (excl < K && excl + seg[t] >= K) {
            unsigned int cum = excl;
            for (int b = 63; b >= 0; --b) {
                unsigned int c = h[t * 64 + b];
                if (cum + c >= K) {
                    params[lev] = (unsigned int)(t * 64 + b);
                    params[8 + lev] = K - cum;
                    params[16 + lev] = 0;
                    break;
                }
                cum += c;
            }
        }
    } else if (t == 0) {
        params[lev] = BIN_NEG;
        params[8 + lev] = 0;
        params[16 + lev] = K - totValid;
    }
}

// ---------------------------------------------------------------- K3
// positional compaction: ballot prefix within block, ONE atomic per
// block per destination (682 total, vs ~9k same-address before).
// Valid: finalist iff bin > B*, tie-buffer iff bin == B*.
// Invalid: finalist iff B*==BIN_NEG and index-rank within level < rNeg.
__global__ __launch_bounds__(256) void k3_compact(const unsigned int* sbits,
        const unsigned int* clsv, const unsigned int* params,
        const unsigned int* invOff, unsigned long long* finKeys,
        unsigned int* ctrs, unsigned long long* bBuf) {
    int blk = blockIdx.x;
    int t = threadIdx.x;
    int a = blk * 256 + t;
    int lev, idx; lvl_of(a, lev, idx);
    unsigned int sb = sbits[a];
    unsigned int cv = clsv[a];
    unsigned int h16 = sb >> 16;
    unsigned int Bs = params[lev];
    unsigned int rNeg = params[16 + lev];
    unsigned int valid = cv >> 31;
    int lane = t & 63, w = t >> 6;
    unsigned long long lt = (1ull << lane) - 1ull;
    __shared__ unsigned int wInv[4], wFin[4], wB[4];
    __shared__ unsigned int baseFin, baseB;
    unsigned long long mInv = __ballot(valid == 0u);
    if (lane == 0) wInv[w] = (unsigned int)__popcll(mInv);
    __syncthreads();
    unsigned int invRank = invOff[blk] + (unsigned int)__popcll(mInv & lt);
    for (int i = 0; i < w; ++i) invRank += wInv[i];
    bool isFin, isB;
    if (valid) {
        isFin = (h16 > Bs);
        isB   = (h16 == Bs);
    } else {
        isFin = (Bs == BIN_NEG) && (invRank < rNeg);
        isB   = false;
    }
    unsigned long long mFin = __ballot(isFin);
    unsigned long long mB   = __ballot(isB);
    if (lane == 0) { wFin[w] = (unsigned int)__popcll(mFin); wB[w] = (unsigned int)__popcll(mB); }
    __syncthreads();
    if (t == 0) {
        unsigned int tf = wFin[0] + wFin[1] + wFin[2] + wFin[3];
        unsigned int tb = wB[0] + wB[1] + wB[2] + wB[3];
        baseFin = tf ? atomicAdd(&ctrs[0], tf) : 0u;
        baseB   = tb ? atomicAdd(&ctrs[1 + lev], tb) : 0u;
    }
    __syncthreads();
    if (isFin || isB) {
        unsigned int composite = ((unsigned int)lev << 16) | (unsigned int)idx;
        unsigned int inv = (~composite) & 0x7FFFFu;
        unsigned int low = (inv << 13) | (valid << 7) | (cv & 0x7Fu);
        unsigned long long key = ((unsigned long long)sb << 32) | low;
        if (isFin) {
            unsigned int p = baseFin + (unsigned int)__popcll(mFin & lt);
            for (int i = 0; i < w; ++i) p += wFin[i];
            if (p < NF) finKeys[p] = key;
        } else {
            unsigned int p = baseB + (unsigned int)__popcll(mB & lt);
            for (int i = 0; i < w; ++i) p += wB[i];
            if (p < BCAP) bBuf[(size_t)lev * BCAP + p] = key;
        }
    }
}

// ---------------------------------------------------------------- K4
// resolve VALID boundary-bin ties (now small: anchors sharing one exact
// 16-bit score bin). one block per level.
__global__ __launch_bounds__(1024) void k4_bound(const unsigned int* params,
        const unsigned long long* bBuf, const unsigned int* bCount,
        unsigned long long* finKeys, unsigned int* finCount) {
    __shared__ unsigned long long k[BCAP];
    int t = threadIdx.x;
    int lev = blockIdx.x;
    unsigned int bc = bCount[lev];
    int n = (bc > BCAP) ? BCAP : (int)bc;
    int r = (int)params[8 + lev];
    if (r > n) r = n;
    int m = 1; while (m < n) m <<= 1;
    for (int i = t; i < m; i += 1024)
        k[i] = (i < n) ? bBuf[(size_t)lev * BCAP + i] : 0ull;
    __syncthreads();
    for (int len = 2; len <= m; len <<= 1) {
        for (int st = len >> 1; st > 0; st >>= 1) {
            for (int i = t; i < m; i += 1024) {
                int j = i ^ st;
                if (j > i) {
                    unsigned long long a = k[i], b = k[j];
                    bool up = ((i & len) == 0);
                    if (up ? (a < b) : (a > b)) { k[i] = b; k[j] = a; }
                }
            }
            __syncthreads();
        }
    }
    for (int i = t; i < r; i += 1024) {
        unsigned int p = atomicAdd(finCount, 1u);
        if (p < NF) finKeys[p] = k[i];
    }
}

// ---------------------------------------------------------------- K5
// rank-by-counting (keys unique) + decode + clip + area/score.
__global__ __launch_bounds__(256) void k5_rank(InPtrs P,
        const unsigned long long* finKeys, float4* sBox, float* sScore,
        unsigned int* sCV, float* sArea) {
    __shared__ unsigned long long keys[NF];
    __shared__ unsigned int rnk[64];
    int t = threadIdx.x;
    for (int i = t; i < NF; i += 256) keys[i] = finKeys[i];
    if (t < 64) rnk[t] = 0;
    __syncthreads();
    int lf = t & 63;
    int seg = t >> 6;
    int f = blockIdx.x * 64 + lf;
    unsigned long long my = (f < NF) ? keys[f] : 0ull;
    if (f < NF) {
        unsigned int c = 0;
        int s0 = seg * 1064, s1 = s0 + 1064;
        for (int i = s0; i < s1; ++i) c += (keys[i] > my) ? 1u : 0u;
        atomicAdd(&rnk[lf], c);
    }
    __syncthreads();
    if (seg == 0 && f < NF) {
        unsigned int r = rnk[lf];
        unsigned int sb  = (unsigned int)(my >> 32);
        unsigned int low = (unsigned int)my;
        unsigned int composite = (~(low >> 13)) & 0x7FFFFu;
        int lev = composite >> 16;
        int idx = composite & 0xFFFF;
        float4 b = ((const float4*)P.reg[lev])[idx];
        float vy1 = P.loc[0], vx1 = P.loc[1], vy2 = P.loc[2], vx2 = P.loc[3];
        float y1 = fmaxf(b.x, vy1), x1 = fmaxf(b.y, vx1);
        float y2 = fminf(b.z, vy2), x2 = fminf(b.w, vx2);
        float area = __fmul_rn(fmaxf(y2 - y1, 0.0f), fmaxf(x2 - x1, 0.0f));
        unsigned int valid = (low >> 7) & 1u;
        sBox[r] = make_float4(y1, x1, y2, x2);
        sScore[r] = valid ? funkey(sb) : 0.0f;
        sCV[r] = (low & 0x7Fu) | (valid << 31);
        sArea[r] = area;
    }
}

// ---------------------------------------------------------------- K6
// sparse adjacency: triangular 1D grid of 64x64 tiles.
__global__ __launch_bounds__(256) void k6_adj(const float4* sBox,
        const float* sArea, unsigned int* cnt, unsigned short* nbr) {
    int L = blockIdx.x;
    float fr = sqrtf(8.0f * (float)L + 1.0f);
    int jt = (int)((fr - 1.0f) * 0.5f);
    while ((jt + 1) * (jt + 2) / 2 <= L) jt++;
    while (jt * (jt + 1) / 2 > L) jt--;
    int it = L - jt * (jt + 1) / 2;
    __shared__ float4 cb[64]; __shared__ float ca[64];
    __shared__ float4 rb[64]; __shared__ float ra[64];
    int t = threadIdx.x;
    if (t < 64) {
        int j = jt * 64 + t;
        if (j < NF) { cb[t] = sBox[j]; ca[t] = sArea[j]; }
        int i = it * 64 + t;
        if (i < NF) { rb[t] = sBox[i]; ra[t] = sArea[i]; }
    }
    __syncthreads();
    int lj = t & 63;
    int j = jt * 64 + lj;
    if (j >= NF) return;
    float4 B = cb[lj]; float ab = ca[lj];
    for (int li = (t >> 6); li < 64; li += 4) {
        int i = it * 64 + li;
        if (i >= j) continue;
        float4 A = rb[li]; float aa = ra[li];
        float iy1 = fmaxf(A.x, B.x), ix1 = fmaxf(A.y, B.y);
        float iy2 = fminf(A.z, B.z), ix2 = fminf(A.w, B.w);
        float ih = fmaxf(iy2 - iy1, 0.0f), iw = fmaxf(ix2 - ix1, 0.0f);
        float inter = __fmul_rn(ih, iw);
        float uni = __fsub_rn(__fadd_rn(aa, ab), inter);
        float iou = __fdiv_rn(inter, fmaxf(uni, 1e-9f));
        if (iou > 0.5f) {
            unsigned int p = atomicAdd(&cnt[j], 1u);
            if (p < CAPD) nbr[(size_t)j * CAPD + p] = (unsigned short)i;
        }
    }
}

// ---------------------------------------------------------------- K7
// CSR into LDS once, 16 all-LDS keep iterations, top-100 emit.
__global__ __launch_bounds__(1024) void k7_nms(InPtrs P, const float4* sBox,
        const float* sScore, const unsigned int* sCV, const unsigned int* cnt,
        const unsigned short* nbr, float* out) {
    __shared__ unsigned char bufA[NF];
    __shared__ unsigned char bufB[NF];
    __shared__ unsigned int csum[1024];
    __shared__ unsigned int off[NF + 1];
    __shared__ unsigned short degs[NF];
    __shared__ unsigned short edges[EC];
    __shared__ float ploc[6];
    int t = threadIdx.x;
    if (t < 6) ploc[t] = P.loc[t];
    for (int j = t; j < NF; j += 1024) {
        unsigned int d = cnt[j]; if (d > CAPD) d = CAPD;
        degs[j] = (unsigned short)d;
        bufA[j] = 1;
    }
    __syncthreads();
    const int CH = 5;
    {
        unsigned int dq[CH]; unsigned int s = 0;
        #pragma unroll
        for (int q = 0; q < CH; ++q) {
            int j = t * CH + q;
            unsigned int d = (j < NF) ? (unsigned int)degs[j] : 0u;
            dq[q] = d; s += d;
        }
        csum[t] = s;
        __syncthreads();
        for (int o = 1; o < 1024; o <<= 1) {
            unsigned int v = csum[t];
            unsigned int add = (t >= o) ? csum[t - o] : 0u;
            __syncthreads();
            csum[t] = v + add;
            __syncthreads();
        }
        unsigned int base = csum[t] - s;
        #pragma unroll
        for (int q = 0; q < CH; ++q) {
            int j = t * CH + q;
            if (j < NF) { off[j] = base; base += dq[q]; }
        }
        if (t == 1023) off[NF] = csum[1023];
    }
    __syncthreads();
    unsigned int E = off[NF];
    bool useLds = (E <= (unsigned int)EC);
    if (useLds) {
        for (int j = t; j < NF; j += 1024) {
            unsigned int o = off[j];
            unsigned int d = degs[j];
            const unsigned short* nl = nbr + (size_t)j * CAPD;
            for (unsigned int e = 0; e < d; ++e) edges[o + e] = nl[e];
        }
    }
    __syncthreads();
    unsigned char* cur = bufA; unsigned char* nxt = bufB;
    for (int itr = 0; itr < NITER; ++itr) {
        if (useLds) {
            for (int j = t; j < NF; j += 1024) {
                unsigned int d = degs[j];
                unsigned int o = off[j];
                unsigned char kp = 1;
                for (unsigned int e = 0; e < d; ++e)
                    if (cur[edges[o + e]]) { kp = 0; break; }
                nxt[j] = kp;
            }
        } else {
            for (int j = t; j < NF; j += 1024) {
                unsigned int d = degs[j];
                const unsigned short* nl = nbr + (size_t)j * CAPD;
                unsigned char kp = 1;
                for (unsigned int e = 0; e < d; ++e)
                    if (cur[nl[e]]) { kp = 0; break; }
                nxt[j] = kp;
            }
        }
        __syncthreads();
        unsigned char* tm = cur; cur = nxt; nxt = tm;
    }
    int base = t * CH;
    unsigned char kf[CH];
    unsigned int sum = 0;
    #pragma unroll
    for (int q = 0; q < CH; ++q) {
        int j = base + q;
        unsigned char v = 0;
        if (j < NF) v = cur[j] & (unsigned char)(sCV[j] >> 31);
        kf[q] = v; sum += v;
    }
    csum[t] = sum;
    __syncthreads();
    for (int o = 1; o < 1024; o <<= 1) {
        unsigned int v = csum[t];
        unsigned int add = (t >= o) ? csum[t - o] : 0u;
        __syncthreads();
        csum[t] = v + add;
        __syncthreads();
    }
    unsigned int keptTot = csum[1023];
    unsigned int run = csum[t] - sum;
    float vy1 = ploc[0], vx1 = ploc[1], vy2 = ploc[2], vx2 = ploc[3];
    float sy = ploc[4] / fmaxf(vy2 - vy1, 1e-6f);
    float sx = ploc[5] / fmaxf(vx2 - vx1, 1e-6f);
    #pragma unroll
    for (int q = 0; q < CH; ++q) {
        int j = base + q;
        if (j >= NF) break;
        unsigned int slot = 0xFFFFFFFFu;
        float sc = 0.0f;
        if (kf[q]) {
            if (run < 100u) { slot = run; sc = sScore[j]; }
            run++;
        } else if (keptTot < 100u) {
            unsigned int nk = (unsigned int)j - run;
            unsigned int s2 = keptTot + nk;
            if (s2 < 100u) { slot = s2; sc = 0.0f; }
        }
        if (slot < 100u) {
            float4 b = sBox[j];
            out[slot * 4 + 0] = (b.x - vy1) * sy;
            out[slot * 4 + 1] = (b.y - vx1) * sx;
            out[slot * 4 + 2] = (b.z - vy1) * sy;
            out[slot * 4 + 3] = (b.w - vx1) * sx;
            out[400 + slot] = (float)(sCV[j] & 0x7Fu);
            out[500 + slot] = sc;
        }
    }
}

extern "C" void kernel_launch(void* const* d_in, const int* in_sizes, int n_in,
                              void* d_out, int out_size, void* d_ws, size_t ws_size,
                              hipStream_t stream) {
    (void)n_in; (void)out_size; (void)ws_size;
    InPtrs P;
    bool inter = (in_sizes[1] == 65536 * 4);
    for (int s = 0; s < 5; ++s) {
        P.cls[s] = (const float*)d_in[inter ? 2 * s : s];
        P.reg[s] = (const float*)d_in[inter ? 2 * s + 1 : 5 + s];
    }
    P.loc = (const float*)d_in[10];

    char* w = (char*)d_ws;
    unsigned int* hist   = (unsigned int*)(w + OFF_HIST);
    unsigned int* cnt    = (unsigned int*)(w + OFF_CNT);
    unsigned int* ctrs   = (unsigned int*)(w + OFF_CTR);
    unsigned int* sbits  = (unsigned int*)(w + OFF_SBITS);
    unsigned int* clsv   = (unsigned int*)(w + OFF_CLSV);
    unsigned int* params = (unsigned int*)(w + OFF_PAR);
    unsigned int* invBlk = (unsigned int*)(w + OFF_INVB);
    unsigned int* invOff = (unsigned int*)(w + OFF_INVO);
    unsigned long long* finKeys = (unsigned long long*)(w + OFF_FINK);
    unsigned long long* bBuf    = (unsigned long long*)(w + OFF_BBUF);
    float4* sBox  = (float4*)(w + OFF_SBOX);
    float* sScore = (float*)(w + OFF_SSC);
    unsigned int* sCV = (unsigned int*)(w + OFF_SCV);
    float* sArea  = (float*)(w + OFF_SAR);
    unsigned short* nbr = (unsigned short*)(w + OFF_NBR);

    hipMemsetAsync(d_ws, 0, ZERO_SZ, stream);
    k1_score<<<NBLK, 1024, 0, stream>>>(P, hist, sbits, clsv, invBlk);
    k2_scan<<<6, 1024, 0, stream>>>(hist, invBlk, params, invOff);
    k3_compact<<<NBLK, 256, 0, stream>>>(sbits, clsv, params, invOff, finKeys, ctrs, bBuf);
    k4_bound<<<5, 1024, 0, stream>>>(params, bBuf, ctrs + 1, finKeys, ctrs);
    k5_rank<<<67, 256, 0, stream>>>(P, finKeys, sBox, sScore, sCV, sArea);
    k6_adj<<<2278, 256, 0, stream>>>(sBox, sArea, cnt, nbr);
    k7_nms<<<1, 1024, 0, stream>>>(P, sBox, sScore, sCV, cnt, nbr, (float*)d_out);
}